// Round 14
// baseline (228.995 us; speedup 1.0000x reference)
//
#include <hip/hip_runtime.h>
#include <stdint.h>

#define ROWLEN 4096
#define KSEL   1024
#define NTHREADS 256
#define NBINS  4096      // 12-bit digit = v >> 20
#define KEYCAP 1536
#define GLCAP  64        // >64 active groups -> fallback (never for N(0,1))
#define JOBCAP 64
typedef unsigned long long u64;

// Monotonic float->uint map: order(f) preserved as unsigned compare.
__device__ __forceinline__ uint32_t f2u_sortable(float f) {
    uint32_t u = __float_as_uint(f);
    return u ^ ((int32_t)u < 0 ? 0xFFFFFFFFu : 0x80000000u);
}

// A32 bank swizzle: involution on word index, preserves 4-word blocks.
__device__ __forceinline__ int aswz(int w) { return w ^ ((w >> 3) & 0x1C); }
__device__ __forceinline__ int swb(int B) { return B ^ ((B >> 3) & 7); }   // block form

__device__ __forceinline__ void cmpex32(uint32_t &a, uint32_t &b, bool maxFirst) {
    uint32_t lo = a < b ? a : b, hi = a < b ? b : a;
    a = maxFirst ? hi : lo;
    b = maxFirst ? lo : hi;
}

// Shuffle stage for 4-elem/lane row-major layout: element i=4*subl+e, lane
// partner subl^(j>>2) within W-lane segment. Keys distinct within a group.
template<int W>
__device__ __forceinline__ uint32_t shst4(uint32_t r, int i, int j, int k) {
    uint32_t o = __shfl_xor(r, j >> 2, W);
    bool takeMax = (((i & j) == 0) == ((i & k) == 0));
    return ((r > o) == takeMax) ? r : o;
}

// Descending bitonic sort of P=2^LOGP keys held as 4 regs/lane (i = 4*subl+e)
// across W=P/4 lanes. j=1,2 in-register; j>=4 via shfl at width W.
template<int LOGP>
__device__ __forceinline__ void sortP4(uint32_t &r0, uint32_t &r1,
                                       uint32_t &r2, uint32_t &r3, int subl) {
    constexpr int P = 1 << LOGP;
    constexpr int W = P >> 2;
    const int i0 = 4 * subl, i1 = i0 + 1, i2 = i0 + 2, i3 = i0 + 3;
#pragma unroll
    for (int k = 2; k <= P; k <<= 1) {
#pragma unroll
        for (int j = k >> 1; j > 0; j >>= 1) {
            if (j == 1) {
                cmpex32(r0, r1, (i0 & k) == 0);
                cmpex32(r2, r3, (i2 & k) == 0);
            } else if (j == 2) {
                cmpex32(r0, r2, (i0 & k) == 0);
                cmpex32(r1, r3, (i1 & k) == 0);
            } else {
                r0 = shst4<W>(r0, i0, j, k);
                r1 = shst4<W>(r1, i1, j, k);
                r2 = shst4<W>(r2, i2, j, k);
                r3 = shst4<W>(r3, i3, j, k);
            }
        }
    }
}

__global__ __launch_bounds__(NTHREADS, 8) void adaptive_topk_kernel(
    const float* __restrict__ in, int* __restrict__ out_idx, int* __restrict__ out_k)
{
    __shared__ uint32_t A32[NBINS / 2];   // 8 KB packed u16 bins (swizzled storage)
    __shared__ uint32_t keys[KEYCAP];     // 6 KB u32 group-scatter keys
    __shared__ uint16_t outbuf[KSEL];     // 2 KB sorted indices staging
    __shared__ uint32_t glist[GLCAP];     // (n<<16)|base per active group
    __shared__ uint32_t glist2[GLCAP];    // class-sorted groups
    __shared__ uint32_t jinfo[JOBCAP];    // type(3b) | start<<3 (6b) | nslots<<9 (5b)
    __shared__ uint32_t wavetot[4];
    __shared__ float wsum[4], wsum2[4];
    __shared__ int sh_d1, sh_ng, sh_fb, sh_nj;

    const int row  = blockIdx.x;
    const int tid  = threadIdx.x;
    const int lane = tid & 63;
    const int wv   = tid >> 6;
    const float* __restrict__ rowp = in + (size_t)row * ROWLEN;
    int* __restrict__ orow = out_idx + (size_t)row * KSEL;
    const float4* r4 = (const float4*)rowp;

    const uint4 z0 = {0u, 0u, 0u, 0u};
    ((uint4*)A32)[tid] = z0;              // clear 2048 words (bijective: order-free)
    ((uint4*)A32)[tid + 256] = z0;
    if (tid == 0) { sh_ng = 0; sh_fb = 0; }
    __syncthreads();

    // ---- pass 1: load row, keep sortable values in 4 NAMED uint4 regs
    //      (static indexing only -> no scratch), histogram + moments ----
    uint4 w0, w1, w2, w3;
    float s = 0.0f, s2 = 0.0f;
#define P1(WI, IT)                                                            \
    {                                                                         \
        float4 v = r4[tid + 256 * (IT)];                                      \
        s += (v.x + v.y) + (v.z + v.w);                                       \
        s2 = fmaf(v.x, v.x, fmaf(v.y, v.y, fmaf(v.z, v.z, fmaf(v.w, v.w, s2))));\
        WI.x = f2u_sortable(v.x); WI.y = f2u_sortable(v.y);                   \
        WI.z = f2u_sortable(v.z); WI.w = f2u_sortable(v.w);                   \
        uint32_t bx = WI.x >> 20, by = WI.y >> 20;                            \
        uint32_t bz = WI.z >> 20, bw = WI.w >> 20;                            \
        atomicAdd(&A32[aswz(bx >> 1)], (bx & 1) ? (1u << 16) : 1u);           \
        atomicAdd(&A32[aswz(by >> 1)], (by & 1) ? (1u << 16) : 1u);           \
        atomicAdd(&A32[aswz(bz >> 1)], (bz & 1) ? (1u << 16) : 1u);           \
        atomicAdd(&A32[aswz(bw >> 1)], (bw & 1) ? (1u << 16) : 1u);           \
    }
    P1(w0, 0) P1(w1, 1) P1(w2, 2) P1(w3, 3)
#undef P1
    for (int off = 32; off > 0; off >>= 1) {
        s  += __shfl_down(s, off);
        s2 += __shfl_down(s2, off);
    }
    if (lane == 0) { wsum[wv] = s; wsum2[wv] = s2; }
    __syncthreads();                      // hist + wsum complete
    if (tid == 0) {
        double S  = (double)wsum[0] + wsum[1] + wsum[2] + wsum[3];
        double S2 = (double)wsum2[0] + wsum2[1] + wsum2[2] + wsum2[3];
        double var = (S2 - S * S / (double)ROWLEN) / (double)(ROWLEN - 1);
        float sp = log1pf(expf((float)var));
        float ka = 512.0f * (1.0f + 0.1f * sp);
        ka = fminf(fmaxf(ka, 128.0f), 1024.0f);
        out_k[row] = (int)ka;
    }

    // ---- suffix scan over 4096 bins; boundary digit d1; bases into A32 ----
    uint32_t hww[8];                       // my 16 bins, packed (static-indexed)
    {
        uint4 h0 = ((uint4*)A32)[swb(2 * tid)];
        uint4 h1 = ((uint4*)A32)[swb(2 * tid + 1)];
        hww[0] = h0.x; hww[1] = h0.y; hww[2] = h0.z; hww[3] = h0.w;
        hww[4] = h1.x; hww[5] = h1.y; hww[6] = h1.z; hww[7] = h1.w;
    }
    uint32_t csum = 0;
#pragma unroll
    for (int q = 0; q < 8; ++q) csum += (hww[q] & 0xFFFFu) + (hww[q] >> 16);
    uint32_t incl = csum;                 // inclusive suffix over chunk sums in wave
#pragma unroll
    for (int off = 1; off < 64; off <<= 1) {
        uint32_t t = __shfl_down(incl, off);
        if (lane + off < 64) incl += t;
    }
    if (lane == 0) wavetot[wv] = incl;
    __syncthreads();
    uint32_t later = 0;
    for (int w2_ = wv + 1; w2_ < 4; ++w2_) later += wavetot[w2_];
    const uint32_t R = (incl - csum) + later;   // elems in bins after my chunk
    // Guard: bins >= d1 live only in chunks with R < KSEL (~75% threads skip).
    if (R < KSEL) {
        uint32_t run = R;
#pragma unroll
        for (int q = 7; q >= 0; --q) {
            uint32_t h_hi = hww[q] >> 16, h_lo = hww[q] & 0xFFFFu;
            uint32_t base_hi = run;
            if (run < KSEL && KSEL <= run + h_hi) sh_d1 = 16 * tid + 2 * q + 1;
            run += h_hi;
            uint32_t base_lo = run;
            if (run < KSEL && KSEL <= run + h_lo) sh_d1 = 16 * tid + 2 * q;
            run += h_lo;
            A32[aswz(8 * tid + q)] = (base_hi << 16) | base_lo;
        }
    }
    __syncthreads();                      // bases + sh_d1 visible

    const int d1 = sh_d1;
    const uint32_t X = ((uint32_t)d1) << 20;   // u >= X  <=>  (u>>20) >= d1, exact

    // ---- group list build (guarded; bases by running subtraction) ----
    if (R < KSEL) {
        uint32_t run2 = R + csum;
#pragma unroll
        for (int b = 0; b < 16; ++b) {
            uint32_t n = (hww[b >> 1] >> ((b & 1) * 16)) & 0xFFFFu;
            run2 -= n;                    // = base of bin g
            int g = 16 * tid + b;
            if (g >= d1 && n > 0) {
                if (n > 256) sh_fb = 1;
                int p = atomicAdd(&sh_ng, 1);
                if (p < GLCAP) glist[p] = (n << 16) | run2;
            }
        }
    }
    // ---- pass 2 FROM REGISTERS: grouped scatter, u32 keys (no reload/f2u) ----
#define P2(U, IDX)                                                            \
    if ((U) >= X) {                                                           \
        int g = (int)((U) >> 20);                                             \
        uint32_t old = atomicAdd(&A32[aswz(g >> 1)], (g & 1) ? (1u << 16) : 1u);\
        uint32_t pos = (g & 1) ? (old >> 16) : (old & 0xFFFFu);               \
        if (pos < KEYCAP)                                                     \
            keys[pos] = ((U) << 12) | (uint32_t)(ROWLEN - 1 - (IDX));         \
    }
    {
        const int b0 = 4 * tid;
        P2(w0.x, b0 + 0)        P2(w0.y, b0 + 1)
        P2(w0.z, b0 + 2)        P2(w0.w, b0 + 3)
        P2(w1.x, b0 + 1024)     P2(w1.y, b0 + 1025)
        P2(w1.z, b0 + 1026)     P2(w1.w, b0 + 1027)
        P2(w2.x, b0 + 2048)     P2(w2.y, b0 + 2049)
        P2(w2.z, b0 + 2050)     P2(w2.w, b0 + 2051)
        P2(w3.x, b0 + 3072)     P2(w3.y, b0 + 3073)
        P2(w3.z, b0 + 3074)     P2(w3.w, b0 + 3075)
    }
#undef P2
    __syncthreads();                      // keys + glist complete

    // ---- wave-parallel packer, one class at a time (single live mask) ----
    if (wv == 0) {
        int ng0 = sh_ng;
        if (ng0 > GLCAP) sh_fb = 1;
        else {
            uint32_t e = (lane < ng0) ? glist[lane] : 0u;
            uint32_t n = e >> 16;
            int cls = (lane >= ng0) ? -1 :
                      (n <= 16) ? 0 : (n <= 32) ? 1 : (n <= 64) ? 2 :
                      (n <= 128) ? 3 : 4;
            const u64 lm = (1ull << lane) - 1ull;
            int pos = -1, start = 0, njl = 0;
#pragma unroll
            for (int c = 0; c < 5; ++c) {
                u64 m = __ballot(cls == c);
                int cnt = __popcll(m);
                if (cls == c) pos = start + __popcll(m & lm);
                if (lane == 0) {
                    int per = 16 >> c;     // groups per job: 16,8,4,2,1
                    for (int q = 0; q < cnt; q += per)
                        jinfo[njl++] = (uint32_t)c | ((uint32_t)(start + q) << 3) |
                                       ((uint32_t)min(per, cnt - q) << 9);
                }
                start += cnt;
            }
            if (pos >= 0) glist2[pos] = e;
            if (lane == 0) sh_nj = njl;
        }
    }
    __syncthreads();                      // jobs + final sh_fb visible

    if (!sh_fb) {
        // ---- five per-type loops, ONE sort instantiation each (no co-live
        //      variants -> no spill); static wave-strided job assignment ----
        const int nj = sh_nj;
#define RUN_SORT_T(TY, LOGP, SH)                                              \
        for (int j = wv; j < nj; j += 4) {                                    \
            uint32_t info = jinfo[j];                                         \
            if ((info & 7u) != (uint32_t)(TY)) continue;                      \
            int st = (int)((info >> 3) & 63u);                                \
            int ns = (int)((info >> 9) & 31u);                                \
            int slot = lane >> (SH), subl = lane & ((1 << (SH)) - 1);         \
            uint32_t e2 = (slot < ns) ? glist2[st + slot] : 0u;               \
            int n = (int)(e2 >> 16), base = (int)(e2 & 0xFFFFu);              \
            const int i0 = 4 * subl, i1 = i0 + 1, i2 = i0 + 2, i3 = i0 + 3;   \
            uint32_t r0 = (i0 < n) ? keys[base + i0] : 0u;                    \
            uint32_t r1 = (i1 < n) ? keys[base + i1] : 0u;                    \
            uint32_t r2 = (i2 < n) ? keys[base + i2] : 0u;                    \
            uint32_t r3 = (i3 < n) ? keys[base + i3] : 0u;                    \
            sortP4<LOGP>(r0, r1, r2, r3, subl);                               \
            int quota = min(n, KSEL - base);                                  \
            if (i0 < quota) outbuf[base + i0] =                               \
                (uint16_t)((ROWLEN - 1) - (int)(r0 & 0xFFFu));                \
            if (i1 < quota) outbuf[base + i1] =                               \
                (uint16_t)((ROWLEN - 1) - (int)(r1 & 0xFFFu));                \
            if (i2 < quota) outbuf[base + i2] =                               \
                (uint16_t)((ROWLEN - 1) - (int)(r2 & 0xFFFu));                \
            if (i3 < quota) outbuf[base + i3] =                               \
                (uint16_t)((ROWLEN - 1) - (int)(r3 & 0xFFFu));                \
        }
        RUN_SORT_T(0, 4, 2)   // P=16,  16 groups/job
        RUN_SORT_T(1, 5, 3)   // P=32,  8 groups/job
        RUN_SORT_T(2, 6, 4)   // P=64,  4 groups/job
        RUN_SORT_T(3, 7, 5)   // P=128, 2 groups/job
        RUN_SORT_T(4, 8, 6)   // P=256, 1 group/job
#undef RUN_SORT_T
        __syncthreads();                  // outbuf complete
        // ---- single coalesced row store: ushort4 (LDS) -> int4 (global) ----
        ushort4 t4 = ((const ushort4*)outbuf)[tid];
        int4 ov = { (int)t4.x, (int)t4.y, (int)t4.z, (int)t4.w };
        ((int4*)orow)[tid] = ov;
    } else {
        // ---- exact cooperative fallback (statistically never taken) ----
        if (tid < 64) {
            u64 prev = ~0ull;
            for (int r = 0; r < KSEL; ++r) {
                u64 best = 0;
                for (int c = lane; c < ROWLEN; c += 64) {
                    u64 K = ((u64)f2u_sortable(rowp[c]) << 12) | (u64)(ROWLEN - 1 - c);
                    if (K < prev && K > best) best = K;
                }
                for (int off = 32; off > 0; off >>= 1) {
                    u64 o = __shfl_xor(best, off, 64);
                    best = best > o ? best : o;
                }
                if (lane == 0) orow[r] = (ROWLEN - 1) - (int)(best & 0xFFFu);
                prev = best;
            }
        }
    }
}

extern "C" void kernel_launch(void* const* d_in, const int* in_sizes, int n_in,
                              void* d_out, int out_size, void* d_ws, size_t ws_size,
                              hipStream_t stream) {
    const float* in = (const float*)d_in[0];
    const int B = in_sizes[0] / (ROWLEN * ROWLEN);   // 4
    const int nrows = B * ROWLEN;                    // 16384
    int* out = (int*)d_out;
    int* out_idx = out;                              // B*L*KSEL
    int* out_k   = out + (size_t)nrows * KSEL;       // B*L
    adaptive_topk_kernel<<<dim3(nrows), dim3(NTHREADS), 0, stream>>>(in, out_idx, out_k);
}

// Round 15
// 182.711 us; speedup vs baseline: 1.2533x; 1.2533x over previous
//
#include <hip/hip_runtime.h>
#include <stdint.h>

#define ROWLEN 4096
#define KSEL   1024
#define NTHREADS 256
#define NBINS  4096      // 12-bit digit = v >> 20
#define KEYCAP 1536
#define GLCAP  64        // >64 active groups -> fallback (never for N(0,1))
#define JOBCAP 64
typedef unsigned long long u64;

// Monotonic float->uint map on raw bits: order preserved as unsigned compare.
__device__ __forceinline__ uint32_t bits2sortable(uint32_t u) {
    return u ^ ((int32_t)u < 0 ? 0xFFFFFFFFu : 0x80000000u);
}
__device__ __forceinline__ uint32_t f2u_sortable(float f) {
    return bits2sortable(__float_as_uint(f));
}

// A32 bank swizzle: involution on word index, preserves 4-word blocks.
__device__ __forceinline__ int aswz(int w) { return w ^ ((w >> 3) & 0x1C); }
__device__ __forceinline__ int swb(int B) { return B ^ ((B >> 3) & 7); }   // block form

__device__ __forceinline__ void cmpex32(uint32_t &a, uint32_t &b, bool maxFirst) {
    uint32_t lo = a < b ? a : b, hi = a < b ? b : a;
    a = maxFirst ? hi : lo;
    b = maxFirst ? lo : hi;
}

// Shuffle stage for 4-elem/lane row-major layout: element i=4*subl+e, lane
// partner subl^(j>>2) within W-lane segment. Keys distinct within a group.
template<int W>
__device__ __forceinline__ uint32_t shst4(uint32_t r, int i, int j, int k) {
    uint32_t o = __shfl_xor(r, j >> 2, W);
    bool takeMax = (((i & j) == 0) == ((i & k) == 0));
    return ((r > o) == takeMax) ? r : o;
}

// Descending bitonic sort of P=2^LOGP keys held as 4 regs/lane (i = 4*subl+e)
// across W=P/4 lanes. j=1,2 in-register; j>=4 via shfl at width W.
template<int LOGP>
__device__ __forceinline__ void sortP4(uint32_t &r0, uint32_t &r1,
                                       uint32_t &r2, uint32_t &r3, int subl) {
    constexpr int P = 1 << LOGP;
    constexpr int W = P >> 2;
    const int i0 = 4 * subl, i1 = i0 + 1, i2 = i0 + 2, i3 = i0 + 3;
#pragma unroll
    for (int k = 2; k <= P; k <<= 1) {
#pragma unroll
        for (int j = k >> 1; j > 0; j >>= 1) {
            if (j == 1) {
                cmpex32(r0, r1, (i0 & k) == 0);
                cmpex32(r2, r3, (i2 & k) == 0);
            } else if (j == 2) {
                cmpex32(r0, r2, (i0 & k) == 0);
                cmpex32(r1, r3, (i1 & k) == 0);
            } else {
                r0 = shst4<W>(r0, i0, j, k);
                r1 = shst4<W>(r1, i1, j, k);
                r2 = shst4<W>(r2, i2, j, k);
                r3 = shst4<W>(r3, i3, j, k);
            }
        }
    }
}

__global__ __launch_bounds__(NTHREADS, 8) void adaptive_topk_kernel(
    const float* __restrict__ in, int* __restrict__ out_idx, int* __restrict__ out_k)
{
    __shared__ uint32_t A32[NBINS / 2];   // 8 KB packed u16 bins (swizzled storage)
    __shared__ uint32_t keys[KEYCAP];     // 6 KB u32 group-scatter keys
    __shared__ uint16_t outbuf[KSEL];     // 2 KB staging: raw (4095-idx) low-12 bits
    __shared__ uint32_t glist[GLCAP];     // (n<<16)|base per active group
    __shared__ uint32_t glist2[GLCAP];    // class-sorted groups
    __shared__ uint32_t jinfo[JOBCAP];    // type(3b) | start<<3 (6b) | nslots<<9 (5b)
    __shared__ uint32_t wavetot[4];
    __shared__ float wsum[4], wsum2[4];
    __shared__ int sh_d1, sh_ng, sh_fb, sh_nj;

    const int row  = blockIdx.x;
    const int tid  = threadIdx.x;
    const int lane = tid & 63;
    const int wv   = tid >> 6;
    const float* __restrict__ rowp = in + (size_t)row * ROWLEN;
    int* __restrict__ orow = out_idx + (size_t)row * KSEL;
    const float4* r4 = (const float4*)rowp;
    const uint4*  ru4 = (const uint4*)rowp;

    const uint4 z0 = {0u, 0u, 0u, 0u};
    ((uint4*)A32)[tid] = z0;              // clear 2048 words (bijective: order-free)
    ((uint4*)A32)[tid + 256] = z0;
    if (tid == 0) { sh_ng = 0; sh_fb = 0; }
    __syncthreads();

    // ---- pass 1 over input: 12-bit histogram (packed u16, swizzled) + moments.
    //      Values NOT kept in registers across the scan (PROVEN scratch hazard:
    //      R5-7/R12/R14 all spilled) - re-read in pass 2 (L2-hot).
    float s = 0.0f, s2 = 0.0f;
#pragma unroll
    for (int it = 0; it < 4; ++it) {
        float4 v = r4[tid + 256 * it];
        s += (v.x + v.y) + (v.z + v.w);
        s2 = fmaf(v.x, v.x, fmaf(v.y, v.y, fmaf(v.z, v.z, fmaf(v.w, v.w, s2))));
        uint32_t bx = f2u_sortable(v.x) >> 20, by = f2u_sortable(v.y) >> 20;
        uint32_t bz = f2u_sortable(v.z) >> 20, bw = f2u_sortable(v.w) >> 20;
        atomicAdd(&A32[aswz(bx >> 1)], (bx & 1) ? (1u << 16) : 1u);
        atomicAdd(&A32[aswz(by >> 1)], (by & 1) ? (1u << 16) : 1u);
        atomicAdd(&A32[aswz(bz >> 1)], (bz & 1) ? (1u << 16) : 1u);
        atomicAdd(&A32[aswz(bw >> 1)], (bw & 1) ? (1u << 16) : 1u);
    }
    for (int off = 32; off > 0; off >>= 1) {
        s  += __shfl_down(s, off);
        s2 += __shfl_down(s2, off);
    }
    if (lane == 0) { wsum[wv] = s; wsum2[wv] = s2; }
    __syncthreads();                      // hist + wsum complete
    if (tid == 0) {
        double S  = (double)wsum[0] + wsum[1] + wsum[2] + wsum[3];
        double S2 = (double)wsum2[0] + wsum2[1] + wsum2[2] + wsum2[3];
        double var = (S2 - S * S / (double)ROWLEN) / (double)(ROWLEN - 1);
        float sp = log1pf(expf((float)var));
        float ka = 512.0f * (1.0f + 0.1f * sp);
        ka = fminf(fmaxf(ka, 128.0f), 1024.0f);
        out_k[row] = (int)ka;
    }

    // ---- suffix scan over 4096 bins; boundary digit d1; bases into A32 ----
    uint32_t hww[8];                       // my 16 bins, packed (static-indexed)
    {
        uint4 h0 = ((uint4*)A32)[swb(2 * tid)];
        uint4 h1 = ((uint4*)A32)[swb(2 * tid + 1)];
        hww[0] = h0.x; hww[1] = h0.y; hww[2] = h0.z; hww[3] = h0.w;
        hww[4] = h1.x; hww[5] = h1.y; hww[6] = h1.z; hww[7] = h1.w;
    }
    uint32_t csum = 0;
#pragma unroll
    for (int q = 0; q < 8; ++q) csum += (hww[q] & 0xFFFFu) + (hww[q] >> 16);
    uint32_t incl = csum;                 // inclusive suffix over chunk sums in wave
#pragma unroll
    for (int off = 1; off < 64; off <<= 1) {
        uint32_t t = __shfl_down(incl, off);
        if (lane + off < 64) incl += t;
    }
    if (lane == 0) wavetot[wv] = incl;
    __syncthreads();
    uint32_t later = 0;
    for (int w2_ = wv + 1; w2_ < 4; ++w2_) later += wavetot[w2_];
    const uint32_t R = (incl - csum) + later;   // elems in bins after my chunk
    // Guard: bins >= d1 live only in chunks with R < KSEL (~75% threads skip).
    if (R < KSEL) {
        uint32_t run = R;
#pragma unroll
        for (int q = 7; q >= 0; --q) {
            uint32_t h_hi = hww[q] >> 16, h_lo = hww[q] & 0xFFFFu;
            uint32_t base_hi = run;
            if (run < KSEL && KSEL <= run + h_hi) sh_d1 = 16 * tid + 2 * q + 1;
            run += h_hi;
            uint32_t base_lo = run;
            if (run < KSEL && KSEL <= run + h_lo) sh_d1 = 16 * tid + 2 * q;
            run += h_lo;
            A32[aswz(8 * tid + q)] = (base_hi << 16) | base_lo;
        }
    }
    __syncthreads();                      // bases + sh_d1 visible

    const int d1 = sh_d1;
    const uint32_t X = ((uint32_t)d1) << 20;   // u >= X  <=>  (u>>20) >= d1, exact

    // ---- group list build (guarded; bases by running subtraction) ----
    if (R < KSEL) {
        uint32_t run2 = R + csum;
#pragma unroll
        for (int b = 0; b < 16; ++b) {
            uint32_t n = (hww[b >> 1] >> ((b & 1) * 16)) & 0xFFFFu;
            run2 -= n;                    // = base of bin g
            int g = 16 * tid + b;
            if (g >= d1 && n > 0) {
                if (n > 256) sh_fb = 1;
                int p = atomicAdd(&sh_ng, 1);
                if (p < GLCAP) glist[p] = (n << 16) | run2;
            }
        }
    }
    // ---- pass 2 over input (L2-hot re-read as uint4): grouped scatter ----
#pragma unroll
    for (int it = 0; it < 4; ++it) {
        uint4 v = ru4[tid + 256 * it];
        const int idx0 = 4 * (tid + 256 * it);
#pragma unroll
        for (int e = 0; e < 4; ++e) {
            uint32_t raw = (e == 0) ? v.x : (e == 1) ? v.y : (e == 2) ? v.z : v.w;
            uint32_t u = bits2sortable(raw);
            if (u >= X) {                  // threshold compare, no shift
                int g = (int)(u >> 20);
                uint32_t old = atomicAdd(&A32[aswz(g >> 1)], (g & 1) ? (1u << 16) : 1u);
                uint32_t pos = (g & 1) ? (old >> 16) : (old & 0xFFFFu);
                if (pos < KEYCAP)
                    keys[pos] = (u << 12) | (uint32_t)(ROWLEN - 1 - (idx0 + e));
            }
        }
    }
    __syncthreads();                      // keys + glist complete

    // ---- wave-parallel packer, one class at a time (single live mask) ----
    if (wv == 0) {
        int ng0 = sh_ng;
        if (ng0 > GLCAP) sh_fb = 1;
        else {
            uint32_t e = (lane < ng0) ? glist[lane] : 0u;
            uint32_t n = e >> 16;
            int cls = (lane >= ng0) ? -1 :
                      (n <= 16) ? 0 : (n <= 32) ? 1 : (n <= 64) ? 2 :
                      (n <= 128) ? 3 : 4;
            const u64 lm = (1ull << lane) - 1ull;
            int pos = -1, start = 0, njl = 0;
#pragma unroll
            for (int c = 0; c < 5; ++c) {
                u64 m = __ballot(cls == c);
                int cnt = __popcll(m);
                if (cls == c) pos = start + __popcll(m & lm);
                if (lane == 0) {
                    int per = 16 >> c;     // groups per job: 16,8,4,2,1
                    for (int q = 0; q < cnt; q += per)
                        jinfo[njl++] = (uint32_t)c | ((uint32_t)(start + q) << 3) |
                                       ((uint32_t)min(per, cnt - q) << 9);
                }
                start += cnt;
            }
            if (pos >= 0) glist2[pos] = e;
            if (lane == 0) sh_nj = njl;
        }
    }
    __syncthreads();                      // jobs + final sh_fb visible

    if (!sh_fb) {
        // ---- five per-type loops, ONE sort instantiation each (no co-live
        //      variants -> no spill); static wave-strided job assignment.
        //      outbuf gets raw low-12 key bits; index flip deferred to store.
        const int nj = sh_nj;
#define RUN_SORT_T(TY, LOGP, SH)                                              \
        for (int j = wv; j < nj; j += 4) {                                    \
            uint32_t info = jinfo[j];                                         \
            if ((info & 7u) != (uint32_t)(TY)) continue;                      \
            int st = (int)((info >> 3) & 63u);                                \
            int ns = (int)((info >> 9) & 31u);                                \
            int slot = lane >> (SH), subl = lane & ((1 << (SH)) - 1);         \
            uint32_t e2 = (slot < ns) ? glist2[st + slot] : 0u;               \
            int n = (int)(e2 >> 16), base = (int)(e2 & 0xFFFFu);              \
            const int i0 = 4 * subl, i1 = i0 + 1, i2 = i0 + 2, i3 = i0 + 3;   \
            uint32_t r0 = (i0 < n) ? keys[base + i0] : 0u;                    \
            uint32_t r1 = (i1 < n) ? keys[base + i1] : 0u;                    \
            uint32_t r2 = (i2 < n) ? keys[base + i2] : 0u;                    \
            uint32_t r3 = (i3 < n) ? keys[base + i3] : 0u;                    \
            sortP4<LOGP>(r0, r1, r2, r3, subl);                               \
            int quota = min(n, KSEL - base);                                  \
            if (i0 < quota) outbuf[base + i0] = (uint16_t)(r0 & 0xFFFu);      \
            if (i1 < quota) outbuf[base + i1] = (uint16_t)(r1 & 0xFFFu);      \
            if (i2 < quota) outbuf[base + i2] = (uint16_t)(r2 & 0xFFFu);      \
            if (i3 < quota) outbuf[base + i3] = (uint16_t)(r3 & 0xFFFu);      \
        }
        RUN_SORT_T(0, 4, 2)   // P=16,  16 groups/job
        RUN_SORT_T(1, 5, 3)   // P=32,  8 groups/job
        RUN_SORT_T(2, 6, 4)   // P=64,  4 groups/job
        RUN_SORT_T(3, 7, 5)   // P=128, 2 groups/job
        RUN_SORT_T(4, 8, 6)   // P=256, 1 group/job
#undef RUN_SORT_T
        __syncthreads();                  // outbuf complete
        // ---- single coalesced row store; apply idx = 4095 - raw here ----
        ushort4 t4 = ((const ushort4*)outbuf)[tid];
        int4 ov = { (ROWLEN - 1) - (int)t4.x, (ROWLEN - 1) - (int)t4.y,
                    (ROWLEN - 1) - (int)t4.z, (ROWLEN - 1) - (int)t4.w };
        ((int4*)orow)[tid] = ov;
    } else {
        // ---- exact cooperative fallback (statistically never taken) ----
        if (tid < 64) {
            u64 prev = ~0ull;
            for (int r = 0; r < KSEL; ++r) {
                u64 best = 0;
                for (int c = lane; c < ROWLEN; c += 64) {
                    u64 K = ((u64)f2u_sortable(rowp[c]) << 12) | (u64)(ROWLEN - 1 - c);
                    if (K < prev && K > best) best = K;
                }
                for (int off = 32; off > 0; off >>= 1) {
                    u64 o = __shfl_xor(best, off, 64);
                    best = best > o ? best : o;
                }
                if (lane == 0) orow[r] = (ROWLEN - 1) - (int)(best & 0xFFFu);
                prev = best;
            }
        }
    }
}

extern "C" void kernel_launch(void* const* d_in, const int* in_sizes, int n_in,
                              void* d_out, int out_size, void* d_ws, size_t ws_size,
                              hipStream_t stream) {
    const float* in = (const float*)d_in[0];
    const int B = in_sizes[0] / (ROWLEN * ROWLEN);   // 4
    const int nrows = B * ROWLEN;                    // 16384
    int* out = (int*)d_out;
    int* out_idx = out;                              // B*L*KSEL
    int* out_k   = out + (size_t)nrows * KSEL;       // B*L
    adaptive_topk_kernel<<<dim3(nrows), dim3(NTHREADS), 0, stream>>>(in, out_idx, out_k);
}